// Round 17
// baseline (184.775 us; speedup 1.0000x reference)
//
#include <hip/hip_runtime.h>
#include <math.h>

#define NEG_SLOPE 0.2f
#define EPS_DEN 1e-16f

typedef __attribute__((ext_vector_type(8))) short bf16x8;
typedef __attribute__((ext_vector_type(4))) float f32x4;

__device__ inline unsigned short f2bf(float f) {   // RNE
    unsigned u = __float_as_uint(f);
    return (unsigned short)((u + 0x7FFFu + ((u >> 16) & 1u)) >> 16);
}
__device__ inline float bflo(unsigned u) { return __uint_as_float(u << 16); }
__device__ inline float bfhi(unsigned u) { return __uint_as_float(u & 0xFFFF0000u); }

// ---------------- fused preprocessing: edge count | x->bf16 | W1 split | W2 split ----------------
__global__ __launch_bounds__(256) void k_pre(const int* __restrict__ ei, int E, int Nn,
                                             int* __restrict__ counts,
                                             const float* __restrict__ x, short* __restrict__ A1, int Mp,
                                             const float* __restrict__ W1, short* __restrict__ B1t,
                                             const float* __restrict__ W2, short* __restrict__ B2t) {
    __shared__ float s[32][33];
    int t = threadIdx.x;
    int b = blockIdx.x;
    int ET = E + Nn;
    int etb = (ET + 255) / 256;
    int xb = (Mp * 64 + 255) / 256;
    if (b < etb) {
        int e = b * 256 + t;
        if (e < ET) {
            int d = (e < E) ? ei[E + e] : (e - E);
            atomicAdd(&counts[d], 1);
        }
        return;
    }
    b -= etb;
    if (b < xb) {
        int i = b * 256 + t;
        if (i < Mp * 64) {
            int row = i >> 6, c = i & 63;
            float v = (row < Nn) ? x[(size_t)row * 64 + c] : 0.f;
            A1[(size_t)row * 64 + c] = (short)f2bf(v);
        }
        return;
    }
    b -= xb;
    const float* W; short* Bt; int K, N, kb, nb;
    if (b < 64) {               // W1: 64x1024 -> B1t [1024][64]
        W = W1; Bt = B1t; K = 64; N = 1024;
        kb = b & 1; nb = b >> 1;
    } else {                    // W2: 1024x512 -> B2t [512][1024]
        b -= 64;
        W = W2; Bt = B2t; K = 1024; N = 512;
        kb = b & 31; nb = b >> 5;
    }
    int k0 = kb * 32, n0 = nb * 32;
    int tx = t & 31, ty = t >> 5;
    for (int r = ty; r < 32; r += 8) s[r][tx] = W[(size_t)(k0 + r) * N + n0 + tx];
    __syncthreads();
    for (int r = ty; r < 32; r += 8) {
        float v = s[tx][r];
        Bt[(size_t)(n0 + r) * K + k0 + tx] = (short)f2bf(v);
    }
}

// ---------------- CSR scan / scatter ----------------
__global__ void k_scan(const int* __restrict__ counts, int Nn, int ET, int* __restrict__ row_off) {
    __shared__ int lds[256];
    int t = threadIdx.x;
    int chunk = (Nn + 255) / 256;
    int b0 = t * chunk, b1 = min(Nn, b0 + chunk);
    int s = 0;
    for (int i = b0; i < b1; i++) s += counts[i];
    lds[t] = s;
    __syncthreads();
    #pragma unroll
    for (int d = 1; d < 256; d <<= 1) {
        int v = (t >= d) ? lds[t - d] : 0;
        __syncthreads();
        lds[t] += v;
        __syncthreads();
    }
    int run = (t == 0) ? 0 : lds[t - 1];
    for (int i = b0; i < b1; i++) { row_off[i] = run; run += counts[i]; }
    if (t == 0) row_off[Nn] = ET;
}

__global__ void k_scatter(const int* __restrict__ ei, int E, int Nn,
                          const int* __restrict__ row_off, int* cursor, int* __restrict__ col) {
    int e = blockIdx.x * blockDim.x + threadIdx.x;
    int ET = E + Nn;
    if (e >= ET) return;
    int d = (e < E) ? ei[E + e] : (e - E);
    int s = (e < E) ? ei[e] : (e - E);
    int pos = atomicAdd(&cursor[d], 1);
    col[row_off[d] + pos] = s;
}

// ---------------- GEMM: 64x128 tile, BK=32, fused scores. HEADC = head width ----------------
template<int HEADC>
__global__ __launch_bounds__(256) void k_mfma_w(const short* __restrict__ A,
                                                const short* __restrict__ B,
                                                unsigned short* __restrict__ C,
                                                const float* __restrict__ a_src,
                                                const float* __restrict__ a_dst,
                                                float* __restrict__ ssrc,
                                                float* __restrict__ sdst,
                                                int M, int N, int Ktot,
                                                int lda, int ldb) {
    __shared__ short As[64 * 32];
    __shared__ short Bs[128 * 32];
    __shared__ float sred[4][64][2];
    int t = threadIdx.x;
    int lane = t & 63;
    int wid = t >> 6;

    int nbx = N >> 7;
    int nb = gridDim.x;
    int q = nb >> 3, r = nb & 7;
    int xcd = blockIdx.x & 7, pos = blockIdx.x >> 3;
    int L = (xcd < r ? xcd * (q + 1) : r * (q + 1) + (xcd - r) * q) + pos;
    int bn = (L % nbx) * 128;
    int bm = (L / nbx) * 64;

    int wm = (wid & 1) * 32, wn = (wid >> 1) * 64;
    int fr = lane & 15, kq = lane >> 4;

    int srow = t >> 2, sslot = t & 3;
    int sko = ((sslot ^ ((srow >> 1) & 3)) << 3);

    f32x4 acc[2][4] = {};

    for (int k0 = 0; k0 < Ktot; k0 += 32) {
        {
            const short* sa = A + (size_t)(bm + srow) * lda + k0 + sko;
            short* da = As + (size_t)(wid << 6) * 8;
            __builtin_amdgcn_global_load_lds((const __attribute__((address_space(1))) void*)sa,
                                             (__attribute__((address_space(3))) void*)da, 16, 0, 0);
            #pragma unroll
            for (int qq = 0; qq < 2; qq++) {
                int v = qq * 256 + t;
                int rowb = v >> 2, slotb = v & 3;
                int skob = ((slotb ^ ((rowb >> 1) & 3)) << 3);
                const short* sb = B + (size_t)(bn + rowb) * ldb + k0 + skob;
                short* db = Bs + (size_t)(qq * 256 + (wid << 6)) * 8;
                __builtin_amdgcn_global_load_lds((const __attribute__((address_space(1))) void*)sb,
                                                 (__attribute__((address_space(3))) void*)db, 16, 0, 0);
            }
        }
        __syncthreads();
        bf16x8 af[2], bfv[4];
        #pragma unroll
        for (int i = 0; i < 2; i++) {
            int rowa = wm + i * 16 + fr;
            af[i] = *(const bf16x8*)(As + rowa * 32 + ((kq ^ ((rowa >> 1) & 3)) << 3));
        }
        #pragma unroll
        for (int j = 0; j < 4; j++) {
            int rowb = wn + j * 16 + fr;
            bfv[j] = *(const bf16x8*)(Bs + rowb * 32 + ((kq ^ ((rowb >> 1) & 3)) << 3));
        }
        #pragma unroll
        for (int i = 0; i < 2; i++)
            #pragma unroll
            for (int j = 0; j < 4; j++)
                acc[i][j] = __builtin_amdgcn_mfma_f32_16x16x32_bf16(af[i], bfv[j], acc[i][j], 0, 0, 0);
        __syncthreads();
    }
    #pragma unroll
    for (int i = 0; i < 2; i++) {
        int rbase = bm + wm + i * 16 + kq * 4;
        #pragma unroll
        for (int j = 0; j < 4; j++) {
            int colc = bn + wn + j * 16 + fr;
            #pragma unroll
            for (int rg = 0; rg < 4; rg++) {
                int rr = rbase + rg;
                if (rr < M) C[(size_t)rr * N + colc] = f2bf(acc[i][j][rg]);
            }
        }
    }
    // fused scores
    float asv[4], adv[4];
    #pragma unroll
    for (int j = 0; j < 4; j++) {
        int colc = bn + wn + j * 16 + fr;
        asv[j] = a_src[colc];
        adv[j] = a_dst[colc];
    }
    float ps[8], pd[8];
    #pragma unroll
    for (int i = 0; i < 2; i++)
        #pragma unroll
        for (int rg = 0; rg < 4; rg++) {
            int k8 = i * 4 + rg;
            ps[k8] = acc[i][0][rg] * asv[0] + acc[i][1][rg] * asv[1]
                   + acc[i][2][rg] * asv[2] + acc[i][3][rg] * asv[3];
            pd[k8] = acc[i][0][rg] * adv[0] + acc[i][1][rg] * adv[1]
                   + acc[i][2][rg] * adv[2] + acc[i][3][rg] * adv[3];
        }
    #pragma unroll
    for (int k8 = 0; k8 < 8; k8++) {
        #pragma unroll
        for (int off = 1; off < 16; off <<= 1) {
            ps[k8] += __shfl_xor(ps[k8], off);
            pd[k8] += __shfl_xor(pd[k8], off);
        }
    }
    if (HEADC == 128) {
        if (fr == 0) {
            #pragma unroll
            for (int i = 0; i < 2; i++)
                #pragma unroll
                for (int rg = 0; rg < 4; rg++) {
                    int rl = wm + i * 16 + kq * 4 + rg;
                    sred[wid][rl][0] = ps[i * 4 + rg];
                    sred[wid][rl][1] = pd[i * 4 + rg];
                }
        }
        __syncthreads();
        if (wid < 2 && fr == 0) {
            int hh = bn >> 7;
            #pragma unroll
            for (int i = 0; i < 2; i++)
                #pragma unroll
                for (int rg = 0; rg < 4; rg++) {
                    int rl = wm + i * 16 + kq * 4 + rg;
                    int rr = bm + rl;
                    if (rr < M) {
                        ssrc[rr * 8 + hh] = sred[wid][rl][0] + sred[wid + 2][rl][0];
                        sdst[rr * 8 + hh] = sred[wid][rl][1] + sred[wid + 2][rl][1];
                    }
                }
        }
    } else {
        int hh = (bn + wn) >> 6;
        if (fr == 0) {
            #pragma unroll
            for (int i = 0; i < 2; i++)
                #pragma unroll
                for (int rg = 0; rg < 4; rg++) {
                    int rr = bm + wm + i * 16 + kq * 4 + rg;
                    if (rr < M) {
                        ssrc[rr * 8 + hh] = ps[i * 4 + rg];
                        sdst[rr * 8 + hh] = pd[i * 4 + rg];
                    }
                }
        }
    }
}

// ---------------- per-edge softmax weights: thread per (n,h) -> exb[j*8+h], inv[n*8+h] ----------------
__global__ __launch_bounds__(256) void k_edge_ex(const float* __restrict__ ssrc,
                                                 const float* __restrict__ sdst,
                                                 const int* __restrict__ col,
                                                 const int* __restrict__ row_off,
                                                 float* __restrict__ exb,
                                                 float* __restrict__ inv, int Nn) {
    int p = blockIdx.x * blockDim.x + threadIdx.x;
    if (p >= Nn * 8) return;
    int n = p >> 3, h = p & 7;
    int beg = row_off[n], end = row_off[n + 1];
    float sd = sdst[p];
    float den = 0.f;
    for (int j = beg; j < end; j++) {
        float s = ssrc[col[j] * 8 + h] + sd;
        s = fmaxf(s, NEG_SLOPE * s);
        float ex = __expf(s);
        exb[(size_t)j * 8 + h] = ex;
        den += ex;
    }
    inv[p] = 1.f / (den + EPS_DEN);
}

// ---------------- layer-1 aggregation: XCD-sliced, 4 slices of 256 cols, precomputed ex ----------------
__global__ __launch_bounds__(256) void k_agg1_x(const unsigned short* __restrict__ hsrc,
                                                const float* __restrict__ exb,
                                                const float* __restrict__ inv,
                                                const int* __restrict__ col,
                                                const int* __restrict__ row_off,
                                                const float* __restrict__ bias,
                                                unsigned short* __restrict__ osp,
                                                int Nn) {
    constexpr int D = 1024;
    int lane = threadIdx.x & 63;
    int wid = threadIdx.x >> 6;
    int xcd = blockIdx.x & 7, pos = blockIdx.x >> 3;
    int slice = xcd & 3;
    int n = pos * 8 + ((xcd >> 2) << 2) + wid;
    if (n >= Nn) return;
    int col0 = slice * 256 + lane * 4;
    int myhead = col0 >> 7;                 // C=128
    int beg = row_off[n], end = row_off[n + 1];
    const unsigned short* hbase = hsrc + col0;

    float acc[4] = {0.f, 0.f, 0.f, 0.f};
    #pragma unroll 4
    for (int j = beg; j < end; j++) {
        int cj = col[j];
        float ex = exb[(size_t)j * 8 + myhead];
        uint2 u = *(const uint2*)(hbase + (size_t)cj * D);
        acc[0] += ex * bflo(u.x); acc[1] += ex * bfhi(u.x);
        acc[2] += ex * bflo(u.y); acc[3] += ex * bfhi(u.y);
    }
    float iv = inv[n * 8 + myhead];
    float vals[4];
    #pragma unroll
    for (int v = 0; v < 4; v++) {
        float val = acc[v] * iv + bias[col0 + v];
        vals[v] = (val > 0.f) ? val : (__expf(val) - 1.f);   // ELU
    }
    uint2 o;
    o.x = (unsigned)f2bf(vals[0]) | ((unsigned)f2bf(vals[1]) << 16);
    o.y = (unsigned)f2bf(vals[2]) | ((unsigned)f2bf(vals[3]) << 16);
    *(uint2*)(osp + (size_t)n * D + col0) = o;
}

// ---------------- layer-2 agg (edge-split 2 waves/node, precomputed ex) + ELU + W3 + l3 state ----------------
__global__ __launch_bounds__(256) void k_agg2_l3(const unsigned short* __restrict__ hsrc,
                                                 const float* __restrict__ exb,
                                                 const float* __restrict__ inv,
                                                 const int* __restrict__ col,
                                                 const int* __restrict__ row_off,
                                                 const float* __restrict__ bias,
                                                 const float* __restrict__ W3,
                                                 const float* __restrict__ as3,
                                                 const float* __restrict__ ad3,
                                                 float4* __restrict__ h3s,
                                                 float* __restrict__ sdst3,
                                                 int Nn) {
    constexpr int D = 512;
    __shared__ float cacc[2][64][8];
    int t = threadIdx.x;
    int lane = t & 63;
    int wid = t >> 6;
    int node_i = wid >> 1, half = wid & 1;
    int n = blockIdx.x * 2 + node_i;
    bool active = (n < Nn);
    int col0 = lane * 8;
    int myhead = lane >> 3;
    float acc[8] = {0.f, 0.f, 0.f, 0.f, 0.f, 0.f, 0.f, 0.f};
    if (active) {
        int beg = row_off[n], end = row_off[n + 1];
        const unsigned short* hbase = hsrc + col0;
        #pragma unroll 4
        for (int j = beg + half; j < end; j += 2) {
            int cj = col[j];
            float ex = exb[(size_t)j * 8 + myhead];
            uint4 u = *(const uint4*)(hbase + (size_t)cj * D);
            acc[0] += ex * bflo(u.x); acc[1] += ex * bfhi(u.x);
            acc[2] += ex * bflo(u.y); acc[3] += ex * bfhi(u.y);
            acc[4] += ex * bflo(u.z); acc[5] += ex * bfhi(u.z);
            acc[6] += ex * bflo(u.w); acc[7] += ex * bfhi(u.w);
        }
    }
    if (half == 1) {
        #pragma unroll
        for (int v = 0; v < 8; v++) cacc[node_i][lane][v] = acc[v];
    }
    __syncthreads();
    if (half == 0 && active) {
        #pragma unroll
        for (int v = 0; v < 8; v++) acc[v] += cacc[node_i][lane][v];
        float iv = inv[n * 8 + myhead];
        float t0 = 0.f, t1 = 0.f, t2 = 0.f;
        #pragma unroll
        for (int v = 0; v < 8; v++) {
            float val = acc[v] * iv + bias[col0 + v];
            val = (val > 0.f) ? val : (__expf(val) - 1.f);
            const float* wp = W3 + (size_t)(col0 + v) * 3;
            t0 += val * wp[0];
            t1 += val * wp[1];
            t2 += val * wp[2];
        }
        #pragma unroll
        for (int off = 32; off >= 1; off >>= 1) {
            t0 += __shfl_xor(t0, off);
            t1 += __shfl_xor(t1, off);
            t2 += __shfl_xor(t2, off);
        }
        if (lane == 0) {
            float s3 = t0 * as3[0] + t1 * as3[1] + t2 * as3[2];
            h3s[n] = make_float4(t0, t1, t2, s3);
            sdst3[n] = t0 * ad3[0] + t1 * ad3[1] + t2 * ad3[2];
        }
    }
}

// ---------------- fused layer-3: 4-lane group per node, packed float4 per edge ----------------
__global__ __launch_bounds__(256) void k_l3_fused(const float4* __restrict__ h3s,
                                                  const float* __restrict__ sdst, const int* __restrict__ col,
                                                  const int* __restrict__ row_off, const float* __restrict__ b3,
                                                  float* __restrict__ out, int Nn) {
    int n = blockIdx.x * 64 + (threadIdx.x >> 2);
    int l4 = threadIdx.x & 3;
    if (n >= Nn) return;
    int beg = row_off[n], end = row_off[n + 1];
    float sd = sdst[n];
    float den = 0.f, a0 = 0.f, a1 = 0.f, a2 = 0.f;
    for (int j = beg + l4; j < end; j += 4) {
        int sI = col[j];
        float4 v = h3s[sI];
        float s = v.w + sd;
        s = fmaxf(s, NEG_SLOPE * s);
        float ex = __expf(s);
        den += ex;
        a0 += ex * v.x;
        a1 += ex * v.y;
        a2 += ex * v.z;
    }
    #pragma unroll
    for (int off = 1; off <= 2; off <<= 1) {
        den += __shfl_xor(den, off);
        a0 += __shfl_xor(a0, off);
        a1 += __shfl_xor(a1, off);
        a2 += __shfl_xor(a2, off);
    }
    if (l4 == 0) {
        float iv = 1.f / (den + EPS_DEN);
        float v0 = a0 * iv + b3[0], v1 = a1 * iv + b3[1], v2 = a2 * iv + b3[2];
        float m = fmaxf(v0, fmaxf(v1, v2));
        float l = logf(__expf(v0 - m) + __expf(v1 - m) + __expf(v2 - m));
        out[n * 3 + 0] = v0 - m - l;
        out[n * 3 + 1] = v1 - m - l;
        out[n * 3 + 2] = v2 - m - l;
    }
}

extern "C" void kernel_launch(void* const* d_in, const int* in_sizes, int n_in,
                              void* d_out, int out_size, void* d_ws, size_t ws_size,
                              hipStream_t stream) {
    (void)n_in; (void)out_size; (void)ws_size;
    const float* x   = (const float*)d_in[0];
    const int*   ei  = (const int*)d_in[1];
    const float* W1  = (const float*)d_in[2];
    const float* as1 = (const float*)d_in[3];
    const float* ad1 = (const float*)d_in[4];
    const float* b1  = (const float*)d_in[5];
    const float* W2  = (const float*)d_in[6];
    const float* as2 = (const float*)d_in[7];
    const float* ad2 = (const float*)d_in[8];
    const float* b2  = (const float*)d_in[9];
    const float* W3  = (const float*)d_in[10];
    const float* as3 = (const float*)d_in[11];
    const float* ad3 = (const float*)d_in[12];
    const float* b3  = (const float*)d_in[13];
    float* out = (float*)d_out;

    const int Nn = in_sizes[0] / 64;   // 10000
    const int E  = in_sizes[1] / 2;    // 160000
    const int ET = E + Nn;
    const int Mp = ((Nn + 127) / 128) * 128;   // 10112

    char* ws = (char*)d_ws;
    size_t off = 0;
    auto alloc = [&](size_t bytes) -> void* {
        void* p = ws + off;
        off = (off + bytes + 255) & ~(size_t)255;
        return p;
    };
    unsigned short* hbuf = (unsigned short*)alloc((size_t)Mp * 1024 * 2);
    unsigned short* A2   = (unsigned short*)alloc((size_t)Mp * 1024 * 2);
    float* exb  = (float*)alloc((size_t)ET * 8 * 4);
    float4* h3s = (float4*)alloc((size_t)Nn * 16);
    short* A1   = (short*)alloc((size_t)Mp * 64 * 2);
    short* B1t  = (short*)alloc((size_t)1024 * 64 * 2);
    short* B2t  = (short*)alloc((size_t)512 * 1024 * 2);
    float* ssrc = (float*)alloc((size_t)Nn * 8 * 4);
    float* sdst = (float*)alloc((size_t)Nn * 8 * 4);
    float* inv  = (float*)alloc((size_t)Nn * 8 * 4);
    float* sdst3= (float*)alloc((size_t)Nn * 4);
    int* counts = (int*)alloc((size_t)Nn * 2 * 4);
    int* cursor = counts + Nn;
    int* row_off= (int*)alloc((size_t)(Nn + 1) * 4);
    int* colb   = (int*)alloc((size_t)ET * 4);

    hipMemsetAsync(counts, 0, (size_t)Nn * 2 * 4, stream);

    int etb = (ET + 255) / 256;
    int xb = (Mp * 64 + 255) / 256;
    int preb = etb + xb + 64 + 512;
    k_pre<<<preb, 256, 0, stream>>>(ei, E, Nn, counts, x, A1, Mp, W1, B1t, W2, B2t);
    k_scan<<<1, 256, 0, stream>>>(counts, Nn, ET, row_off);
    k_scatter<<<etb, 256, 0, stream>>>(ei, E, Nn, row_off, cursor, colb);

    int nwh = (Nn * 8 + 255) / 256;

    // ---- layer 1: 64 -> 8x128 concat (plain bf16 GEMM, scores fused) ----
    {
        int nb = (1024 / 128) * (Mp / 64);
        k_mfma_w<128><<<nb, 256, 0, stream>>>(A1, B1t, hbuf, as1, ad1, ssrc, sdst,
                                              Nn, 1024, 64, 64, 64);
        k_edge_ex<<<nwh, 256, 0, stream>>>(ssrc, sdst, colb, row_off, exb, inv, Nn);
        int nblk = (Nn + 7) / 8 * 8;
        k_agg1_x<<<nblk, 256, 0, stream>>>(hbuf, exb, inv, colb, row_off, b1, A2, Nn);
    }
    // ---- layer 2: 1024 -> 8x64 concat (plain bf16 GEMM 64x128 tile, scores fused) ----
    {
        int nb = (512 / 128) * (Mp / 64);
        k_mfma_w<64><<<nb, 256, 0, stream>>>((const short*)A2, B2t, hbuf, as2, ad2, ssrc, sdst,
                                             Nn, 512, 1024, 1024, 1024);
        k_edge_ex<<<nwh, 256, 0, stream>>>(ssrc, sdst, colb, row_off, exb, inv, Nn);
        k_agg2_l3<<<(Nn + 1) / 2, 256, 0, stream>>>(hbuf, exb, inv, colb, row_off, b2,
                                                    W3, as3, ad3, h3s, sdst3, Nn);
    }
    // ---- layer 3: segment softmax + aggregate + log_softmax ----
    k_l3_fused<<<(Nn + 63) / 64, 256, 0, stream>>>(h3s, sdst3, colb, row_off, b3, out, Nn);
}

// Round 18
// 176.571 us; speedup vs baseline: 1.0465x; 1.0465x over previous
//
#include <hip/hip_runtime.h>
#include <math.h>

#define NEG_SLOPE 0.2f
#define EPS_DEN 1e-16f

typedef __attribute__((ext_vector_type(8))) short bf16x8;
typedef __attribute__((ext_vector_type(4))) float f32x4;

__device__ inline unsigned short f2bf(float f) {   // RNE
    unsigned u = __float_as_uint(f);
    return (unsigned short)((u + 0x7FFFu + ((u >> 16) & 1u)) >> 16);
}
__device__ inline float bflo(unsigned u) { return __uint_as_float(u << 16); }
__device__ inline float bfhi(unsigned u) { return __uint_as_float(u & 0xFFFF0000u); }

// ---------------- fused preprocessing: edge count | x->bf16 | W1 split | W2 split ----------------
__global__ __launch_bounds__(256) void k_pre(const int* __restrict__ ei, int E, int Nn,
                                             int* __restrict__ counts,
                                             const float* __restrict__ x, short* __restrict__ A1, int Mp,
                                             const float* __restrict__ W1, short* __restrict__ B1t,
                                             const float* __restrict__ W2, short* __restrict__ B2t) {
    __shared__ float s[32][33];
    int t = threadIdx.x;
    int b = blockIdx.x;
    int ET = E + Nn;
    int etb = (ET + 255) / 256;
    int xb = (Mp * 64 + 255) / 256;
    if (b < etb) {
        int e = b * 256 + t;
        if (e < ET) {
            int d = (e < E) ? ei[E + e] : (e - E);
            atomicAdd(&counts[d], 1);
        }
        return;
    }
    b -= etb;
    if (b < xb) {
        int i = b * 256 + t;
        if (i < Mp * 64) {
            int row = i >> 6, c = i & 63;
            float v = (row < Nn) ? x[(size_t)row * 64 + c] : 0.f;
            A1[(size_t)row * 64 + c] = (short)f2bf(v);
        }
        return;
    }
    b -= xb;
    const float* W; short* Bt; int K, N, kb, nb;
    if (b < 64) {               // W1: 64x1024 -> B1t [1024][64]
        W = W1; Bt = B1t; K = 64; N = 1024;
        kb = b & 1; nb = b >> 1;
    } else {                    // W2: 1024x512 -> B2t [512][1024]
        b -= 64;
        W = W2; Bt = B2t; K = 1024; N = 512;
        kb = b & 31; nb = b >> 5;
    }
    int k0 = kb * 32, n0 = nb * 32;
    int tx = t & 31, ty = t >> 5;
    for (int r = ty; r < 32; r += 8) s[r][tx] = W[(size_t)(k0 + r) * N + n0 + tx];
    __syncthreads();
    for (int r = ty; r < 32; r += 8) {
        float v = s[tx][r];
        Bt[(size_t)(n0 + r) * K + k0 + tx] = (short)f2bf(v);
    }
}

// ---------------- CSR scan / scatter ----------------
__global__ void k_scan(const int* __restrict__ counts, int Nn, int ET, int* __restrict__ row_off) {
    __shared__ int lds[256];
    int t = threadIdx.x;
    int chunk = (Nn + 255) / 256;
    int b0 = t * chunk, b1 = min(Nn, b0 + chunk);
    int s = 0;
    for (int i = b0; i < b1; i++) s += counts[i];
    lds[t] = s;
    __syncthreads();
    #pragma unroll
    for (int d = 1; d < 256; d <<= 1) {
        int v = (t >= d) ? lds[t - d] : 0;
        __syncthreads();
        lds[t] += v;
        __syncthreads();
    }
    int run = (t == 0) ? 0 : lds[t - 1];
    for (int i = b0; i < b1; i++) { row_off[i] = run; run += counts[i]; }
    if (t == 0) row_off[Nn] = ET;
}

__global__ void k_scatter(const int* __restrict__ ei, int E, int Nn,
                          const int* __restrict__ row_off, int* cursor, int* __restrict__ col) {
    int e = blockIdx.x * blockDim.x + threadIdx.x;
    int ET = E + Nn;
    if (e >= ET) return;
    int d = (e < E) ? ei[E + e] : (e - E);
    int s = (e < E) ? ei[e] : (e - E);
    int pos = atomicAdd(&cursor[d], 1);
    col[row_off[d] + pos] = s;
}

// ---------------- GEMM: 64x128 tile, BK=32, fused scores. HEADC = head width ----------------
template<int HEADC>
__global__ __launch_bounds__(256) void k_mfma_w(const short* __restrict__ A,
                                                const short* __restrict__ B,
                                                unsigned short* __restrict__ C,
                                                const float* __restrict__ a_src,
                                                const float* __restrict__ a_dst,
                                                float* __restrict__ ssrc,
                                                float* __restrict__ sdst,
                                                int M, int N, int Ktot,
                                                int lda, int ldb) {
    __shared__ short As[64 * 32];
    __shared__ short Bs[128 * 32];
    __shared__ float sred[4][64][2];
    int t = threadIdx.x;
    int lane = t & 63;
    int wid = t >> 6;

    int nbx = N >> 7;
    int nb = gridDim.x;
    int q = nb >> 3, r = nb & 7;
    int xcd = blockIdx.x & 7, pos = blockIdx.x >> 3;
    int L = (xcd < r ? xcd * (q + 1) : r * (q + 1) + (xcd - r) * q) + pos;
    int bn = (L % nbx) * 128;
    int bm = (L / nbx) * 64;

    int wm = (wid & 1) * 32, wn = (wid >> 1) * 64;
    int fr = lane & 15, kq = lane >> 4;

    int srow = t >> 2, sslot = t & 3;
    int sko = ((sslot ^ ((srow >> 1) & 3)) << 3);

    f32x4 acc[2][4] = {};

    for (int k0 = 0; k0 < Ktot; k0 += 32) {
        {
            const short* sa = A + (size_t)(bm + srow) * lda + k0 + sko;
            short* da = As + (size_t)(wid << 6) * 8;
            __builtin_amdgcn_global_load_lds((const __attribute__((address_space(1))) void*)sa,
                                             (__attribute__((address_space(3))) void*)da, 16, 0, 0);
            #pragma unroll
            for (int qq = 0; qq < 2; qq++) {
                int v = qq * 256 + t;
                int rowb = v >> 2, slotb = v & 3;
                int skob = ((slotb ^ ((rowb >> 1) & 3)) << 3);
                const short* sb = B + (size_t)(bn + rowb) * ldb + k0 + skob;
                short* db = Bs + (size_t)(qq * 256 + (wid << 6)) * 8;
                __builtin_amdgcn_global_load_lds((const __attribute__((address_space(1))) void*)sb,
                                                 (__attribute__((address_space(3))) void*)db, 16, 0, 0);
            }
        }
        __syncthreads();
        bf16x8 af[2], bfv[4];
        #pragma unroll
        for (int i = 0; i < 2; i++) {
            int rowa = wm + i * 16 + fr;
            af[i] = *(const bf16x8*)(As + rowa * 32 + ((kq ^ ((rowa >> 1) & 3)) << 3));
        }
        #pragma unroll
        for (int j = 0; j < 4; j++) {
            int rowb = wn + j * 16 + fr;
            bfv[j] = *(const bf16x8*)(Bs + rowb * 32 + ((kq ^ ((rowb >> 1) & 3)) << 3));
        }
        #pragma unroll
        for (int i = 0; i < 2; i++)
            #pragma unroll
            for (int j = 0; j < 4; j++)
                acc[i][j] = __builtin_amdgcn_mfma_f32_16x16x32_bf16(af[i], bfv[j], acc[i][j], 0, 0, 0);
        __syncthreads();
    }
    #pragma unroll
    for (int i = 0; i < 2; i++) {
        int rbase = bm + wm + i * 16 + kq * 4;
        #pragma unroll
        for (int j = 0; j < 4; j++) {
            int colc = bn + wn + j * 16 + fr;
            #pragma unroll
            for (int rg = 0; rg < 4; rg++) {
                int rr = rbase + rg;
                if (rr < M) C[(size_t)rr * N + colc] = f2bf(acc[i][j][rg]);
            }
        }
    }
    // fused scores
    float asv[4], adv[4];
    #pragma unroll
    for (int j = 0; j < 4; j++) {
        int colc = bn + wn + j * 16 + fr;
        asv[j] = a_src[colc];
        adv[j] = a_dst[colc];
    }
    float ps[8], pd[8];
    #pragma unroll
    for (int i = 0; i < 2; i++)
        #pragma unroll
        for (int rg = 0; rg < 4; rg++) {
            int k8 = i * 4 + rg;
            ps[k8] = acc[i][0][rg] * asv[0] + acc[i][1][rg] * asv[1]
                   + acc[i][2][rg] * asv[2] + acc[i][3][rg] * asv[3];
            pd[k8] = acc[i][0][rg] * adv[0] + acc[i][1][rg] * adv[1]
                   + acc[i][2][rg] * adv[2] + acc[i][3][rg] * adv[3];
        }
    #pragma unroll
    for (int k8 = 0; k8 < 8; k8++) {
        #pragma unroll
        for (int off = 1; off < 16; off <<= 1) {
            ps[k8] += __shfl_xor(ps[k8], off);
            pd[k8] += __shfl_xor(pd[k8], off);
        }
    }
    if (HEADC == 128) {
        if (fr == 0) {
            #pragma unroll
            for (int i = 0; i < 2; i++)
                #pragma unroll
                for (int rg = 0; rg < 4; rg++) {
                    int rl = wm + i * 16 + kq * 4 + rg;
                    sred[wid][rl][0] = ps[i * 4 + rg];
                    sred[wid][rl][1] = pd[i * 4 + rg];
                }
        }
        __syncthreads();
        if (wid < 2 && fr == 0) {
            int hh = bn >> 7;
            #pragma unroll
            for (int i = 0; i < 2; i++)
                #pragma unroll
                for (int rg = 0; rg < 4; rg++) {
                    int rl = wm + i * 16 + kq * 4 + rg;
                    int rr = bm + rl;
                    if (rr < M) {
                        ssrc[rr * 8 + hh] = sred[wid][rl][0] + sred[wid + 2][rl][0];
                        sdst[rr * 8 + hh] = sred[wid][rl][1] + sred[wid + 2][rl][1];
                    }
                }
        }
    } else {
        int hh = (bn + wn) >> 6;
        if (fr == 0) {
            #pragma unroll
            for (int i = 0; i < 2; i++)
                #pragma unroll
                for (int rg = 0; rg < 4; rg++) {
                    int rr = bm + wm + i * 16 + kq * 4 + rg;
                    if (rr < M) {
                        ssrc[rr * 8 + hh] = ps[i * 4 + rg];
                        sdst[rr * 8 + hh] = pd[i * 4 + rg];
                    }
                }
        }
    }
}

// ---------------- layer-1 aggregation: XCD-sliced, chunked shfl score broadcast ----------------
// block b: xcd=b&7, slice=xcd&3 (5MB L2 set); node = pos*8 + (xcd>>2)*4 + wid.
// Lane owns 4 cols. 32-lane head-groups: lane l32 computes score for edge j0+l32,
// broadcast via shfl -> 1 gather+exp per 32 edges.
__global__ __launch_bounds__(256) void k_agg1_x(const unsigned short* __restrict__ hsrc,
                                                const float* __restrict__ ssrc,
                                                const float* __restrict__ sdst,
                                                const int* __restrict__ col,
                                                const int* __restrict__ row_off,
                                                const float* __restrict__ bias,
                                                unsigned short* __restrict__ osp,
                                                int Nn) {
    constexpr int D = 1024;
    int lane = threadIdx.x & 63;
    int wid = threadIdx.x >> 6;
    int xcd = blockIdx.x & 7, pos = blockIdx.x >> 3;
    int slice = xcd & 3;
    int n = pos * 8 + ((xcd >> 2) << 2) + wid;
    if (n >= Nn) return;
    int col0 = slice * 256 + lane * 4;
    int myhead = (slice << 1) | (lane >> 5);
    int l32 = lane & 31;
    float sd = sdst[n * 8 + myhead];
    int beg = row_off[n], end = row_off[n + 1];
    const unsigned short* hbase = hsrc + col0;

    float acc[4] = {0.f, 0.f, 0.f, 0.f};
    float denp = 0.f;
    for (int j0 = beg; j0 < end; j0 += 32) {
        int nb2 = min(32, end - j0);
        float exm = 0.f; int cjm = 0;
        if (l32 < nb2) {
            cjm = col[j0 + l32];
            float s = ssrc[cjm * 8 + myhead] + sd;
            s = fmaxf(s, NEG_SLOPE * s);
            exm = __expf(s);
        }
        denp += exm;
        #pragma unroll 4
        for (int i = 0; i < nb2; i++) {
            float ex = __shfl(exm, i, 32);
            int cj = __shfl(cjm, i, 32);
            uint2 u = *(const uint2*)(hbase + (size_t)cj * D);
            acc[0] += ex * bflo(u.x); acc[1] += ex * bfhi(u.x);
            acc[2] += ex * bflo(u.y); acc[3] += ex * bfhi(u.y);
        }
    }
    #pragma unroll
    for (int off = 16; off >= 1; off >>= 1) denp += __shfl_xor(denp, off, 32);
    float iv = 1.f / (denp + EPS_DEN);
    float vals[4];
    #pragma unroll
    for (int v = 0; v < 4; v++) {
        float val = acc[v] * iv + bias[col0 + v];
        vals[v] = (val > 0.f) ? val : (__expf(val) - 1.f);   // ELU
    }
    uint2 o;
    o.x = (unsigned)f2bf(vals[0]) | ((unsigned)f2bf(vals[1]) << 16);
    o.y = (unsigned)f2bf(vals[2]) | ((unsigned)f2bf(vals[3]) << 16);
    *(uint2*)(osp + (size_t)n * D + col0) = o;
}

// ---------------- layer-2 agg: wave per node, 8-wide chunked shfl scores + ELU + W3 + l3 state ----------------
__global__ __launch_bounds__(256) void k_agg2_l3(const unsigned short* __restrict__ hsrc,
                                                 const float* __restrict__ ssrc,
                                                 const float* __restrict__ sdst,
                                                 const int* __restrict__ col,
                                                 const int* __restrict__ row_off,
                                                 const float* __restrict__ bias,
                                                 const float* __restrict__ W3,
                                                 const float* __restrict__ as3,
                                                 const float* __restrict__ ad3,
                                                 float4* __restrict__ h3s,
                                                 float* __restrict__ sdst3,
                                                 int Nn) {
    constexpr int D = 512;
    int lane = threadIdx.x & 63;
    int n = blockIdx.x * 4 + (threadIdx.x >> 6);
    if (n >= Nn) return;
    int col0 = lane * 8;
    int myhead = lane >> 3;
    int l8 = lane & 7;
    float sd = sdst[n * 8 + myhead];
    int beg = row_off[n], end = row_off[n + 1];
    const unsigned short* hbase = hsrc + col0;

    float acc[8] = {0.f, 0.f, 0.f, 0.f, 0.f, 0.f, 0.f, 0.f};
    float denp = 0.f;
    for (int j0 = beg; j0 < end; j0 += 8) {
        int nb2 = min(8, end - j0);
        float exm = 0.f; int cjm = 0;
        if (l8 < nb2) {
            cjm = col[j0 + l8];
            float s = ssrc[cjm * 8 + myhead] + sd;
            s = fmaxf(s, NEG_SLOPE * s);
            exm = __expf(s);
        }
        denp += exm;
        #pragma unroll 4
        for (int i = 0; i < nb2; i++) {
            float ex = __shfl(exm, i, 8);
            int cj = __shfl(cjm, i, 8);
            uint4 u = *(const uint4*)(hbase + (size_t)cj * D);
            acc[0] += ex * bflo(u.x); acc[1] += ex * bfhi(u.x);
            acc[2] += ex * bflo(u.y); acc[3] += ex * bfhi(u.y);
            acc[4] += ex * bflo(u.z); acc[5] += ex * bfhi(u.z);
            acc[6] += ex * bflo(u.w); acc[7] += ex * bfhi(u.w);
        }
    }
    #pragma unroll
    for (int off = 4; off >= 1; off >>= 1) denp += __shfl_xor(denp, off, 8);
    float iv = 1.f / (denp + EPS_DEN);
    float t0 = 0.f, t1 = 0.f, t2 = 0.f;
    #pragma unroll
    for (int v = 0; v < 8; v++) {
        float val = acc[v] * iv + bias[col0 + v];
        val = (val > 0.f) ? val : (__expf(val) - 1.f);   // ELU
        const float* wp = W3 + (size_t)(col0 + v) * 3;
        t0 += val * wp[0];
        t1 += val * wp[1];
        t2 += val * wp[2];
    }
    #pragma unroll
    for (int off = 32; off >= 1; off >>= 1) {
        t0 += __shfl_xor(t0, off);
        t1 += __shfl_xor(t1, off);
        t2 += __shfl_xor(t2, off);
    }
    if (lane == 0) {
        float s3 = t0 * as3[0] + t1 * as3[1] + t2 * as3[2];
        h3s[n] = make_float4(t0, t1, t2, s3);
        sdst3[n] = t0 * ad3[0] + t1 * ad3[1] + t2 * ad3[2];
    }
}

// ---------------- fused layer-3: 4-lane group per node, packed float4 per edge ----------------
__global__ __launch_bounds__(256) void k_l3_fused(const float4* __restrict__ h3s,
                                                  const float* __restrict__ sdst, const int* __restrict__ col,
                                                  const int* __restrict__ row_off, const float* __restrict__ b3,
                                                  float* __restrict__ out, int Nn) {
    int n = blockIdx.x * 64 + (threadIdx.x >> 2);
    int l4 = threadIdx.x & 3;
    if (n >= Nn) return;
    int beg = row_off[n], end = row_off[n + 1];
    float sd = sdst[n];
    float den = 0.f, a0 = 0.f, a1 = 0.f, a2 = 0.f;
    for (int j = beg + l4; j < end; j += 4) {
        int sI = col[j];
        float4 v = h3s[sI];
        float s = v.w + sd;
        s = fmaxf(s, NEG_SLOPE * s);
        float ex = __expf(s);
        den += ex;
        a0 += ex * v.x;
        a1 += ex * v.y;
        a2 += ex * v.z;
    }
    #pragma unroll
    for (int off = 1; off <= 2; off <<= 1) {
        den += __shfl_xor(den, off);
        a0 += __shfl_xor(a0, off);
        a1 += __shfl_xor(a1, off);
        a2 += __shfl_xor(a2, off);
    }
    if (l4 == 0) {
        float iv = 1.f / (den + EPS_DEN);
        float v0 = a0 * iv + b3[0], v1 = a1 * iv + b3[1], v2 = a2 * iv + b3[2];
        float m = fmaxf(v0, fmaxf(v1, v2));
        float l = logf(__expf(v0 - m) + __expf(v1 - m) + __expf(v2 - m));
        out[n * 3 + 0] = v0 - m - l;
        out[n * 3 + 1] = v1 - m - l;
        out[n * 3 + 2] = v2 - m - l;
    }
}

extern "C" void kernel_launch(void* const* d_in, const int* in_sizes, int n_in,
                              void* d_out, int out_size, void* d_ws, size_t ws_size,
                              hipStream_t stream) {
    (void)n_in; (void)out_size; (void)ws_size;
    const float* x   = (const float*)d_in[0];
    const int*   ei  = (const int*)d_in[1];
    const float* W1  = (const float*)d_in[2];
    const float* as1 = (const float*)d_in[3];
    const float* ad1 = (const float*)d_in[4];
    const float* b1  = (const float*)d_in[5];
    const float* W2  = (const float*)d_in[6];
    const float* as2 = (const float*)d_in[7];
    const float* ad2 = (const float*)d_in[8];
    const float* b2  = (const float*)d_in[9];
    const float* W3  = (const float*)d_in[10];
    const float* as3 = (const float*)d_in[11];
    const float* ad3 = (const float*)d_in[12];
    const float* b3  = (const float*)d_in[13];
    float* out = (float*)d_out;

    const int Nn = in_sizes[0] / 64;   // 10000
    const int E  = in_sizes[1] / 2;    // 160000
    const int ET = E + Nn;
    const int Mp = ((Nn + 127) / 128) * 128;   // 10112

    char* ws = (char*)d_ws;
    size_t off = 0;
    auto alloc = [&](size_t bytes) -> void* {
        void* p = ws + off;
        off = (off + bytes + 255) & ~(size_t)255;
        return p;
    };
    unsigned short* hbuf = (unsigned short*)alloc((size_t)Mp * 1024 * 2);
    unsigned short* A2   = (unsigned short*)alloc((size_t)Mp * 1024 * 2);
    float4* h3s = (float4*)alloc((size_t)Nn * 16);
    short* A1   = (short*)alloc((size_t)Mp * 64 * 2);
    short* B1t  = (short*)alloc((size_t)1024 * 64 * 2);
    short* B2t  = (short*)alloc((size_t)512 * 1024 * 2);
    float* ssrc = (float*)alloc((size_t)Nn * 8 * 4);
    float* sdst = (float*)alloc((size_t)Nn * 8 * 4);
    float* ssrcB= (float*)alloc((size_t)Nn * 8 * 4);
    float* sdstB= (float*)alloc((size_t)Nn * 8 * 4);
    float* sdst3= (float*)alloc((size_t)Nn * 4);
    int* counts = (int*)alloc((size_t)Nn * 2 * 4);
    int* cursor = counts + Nn;
    int* row_off= (int*)alloc((size_t)(Nn + 1) * 4);
    int* colb   = (int*)alloc((size_t)ET * 4);

    hipMemsetAsync(counts, 0, (size_t)Nn * 2 * 4, stream);

    int etb = (ET + 255) / 256;
    int xb = (Mp * 64 + 255) / 256;
    int preb = etb + xb + 64 + 512;
    k_pre<<<preb, 256, 0, stream>>>(ei, E, Nn, counts, x, A1, Mp, W1, B1t, W2, B2t);
    k_scan<<<1, 256, 0, stream>>>(counts, Nn, ET, row_off);
    k_scatter<<<etb, 256, 0, stream>>>(ei, E, Nn, row_off, cursor, colb);

    // ---- layer 1: 64 -> 8x128 concat (plain bf16 GEMM, scores fused) ----
    {
        int nb = (1024 / 128) * (Mp / 64);
        k_mfma_w<128><<<nb, 256, 0, stream>>>(A1, B1t, hbuf, as1, ad1, ssrc, sdst,
                                              Nn, 1024, 64, 64, 64);
        int nblk = (Nn + 7) / 8 * 8;
        k_agg1_x<<<nblk, 256, 0, stream>>>(hbuf, ssrc, sdst, colb, row_off, b1, A2, Nn);
    }
    // ---- layer 2: 1024 -> 8x64 concat (plain bf16 GEMM 64x128 tile, scores fused) ----
    {
        int nb = (512 / 128) * (Mp / 64);
        k_mfma_w<64><<<nb, 256, 0, stream>>>((const short*)A2, B2t, hbuf, as2, ad2, ssrcB, sdstB,
                                             Nn, 512, 1024, 1024, 1024);
        k_agg2_l3<<<(Nn + 3) / 4, 256, 0, stream>>>(hbuf, ssrcB, sdstB, colb, row_off, b2,
                                                    W3, as3, ad3, h3s, sdst3, Nn);
    }
    // ---- layer 3: segment softmax + aggregate + log_softmax ----
    k_l3_fused<<<(Nn + 63) / 64, 256, 0, stream>>>(h3s, sdst3, colb, row_off, b3, out, Nn);
}

// Round 19
// 162.825 us; speedup vs baseline: 1.1348x; 1.0844x over previous
//
#include <hip/hip_runtime.h>
#include <math.h>

#define NEG_SLOPE 0.2f
#define EPS_DEN 1e-16f

typedef __attribute__((ext_vector_type(8))) short bf16x8;
typedef __attribute__((ext_vector_type(4))) float f32x4;

__device__ inline unsigned short f2bf(float f) {   // RNE
    unsigned u = __float_as_uint(f);
    return (unsigned short)((u + 0x7FFFu + ((u >> 16) & 1u)) >> 16);
}
__device__ inline float bflo(unsigned u) { return __uint_as_float(u << 16); }
__device__ inline float bfhi(unsigned u) { return __uint_as_float(u & 0xFFFF0000u); }

// ---------------- fused preprocessing: edge count | x->bf16 | W1 split | W2 split ----------------
__global__ __launch_bounds__(256) void k_pre(const int* __restrict__ ei, int E, int Nn,
                                             int* __restrict__ counts,
                                             const float* __restrict__ x, short* __restrict__ A1, int Mp,
                                             const float* __restrict__ W1, short* __restrict__ B1t,
                                             const float* __restrict__ W2, short* __restrict__ B2t) {
    __shared__ float s[32][33];
    int t = threadIdx.x;
    int b = blockIdx.x;
    int ET = E + Nn;
    int etb = (ET + 255) / 256;
    int xb = (Mp * 64 + 255) / 256;
    if (b < etb) {
        int e = b * 256 + t;
        if (e < ET) {
            int d = (e < E) ? ei[E + e] : (e - E);
            atomicAdd(&counts[d], 1);
        }
        return;
    }
    b -= etb;
    if (b < xb) {
        int i = b * 256 + t;
        if (i < Mp * 64) {
            int row = i >> 6, c = i & 63;
            float v = (row < Nn) ? x[(size_t)row * 64 + c] : 0.f;
            A1[(size_t)row * 64 + c] = (short)f2bf(v);
        }
        return;
    }
    b -= xb;
    const float* W; short* Bt; int K, N, kb, nb;
    if (b < 64) {               // W1: 64x1024 -> B1t [1024][64]
        W = W1; Bt = B1t; K = 64; N = 1024;
        kb = b & 1; nb = b >> 1;
    } else {                    // W2: 1024x512 -> B2t [512][1024]
        b -= 64;
        W = W2; Bt = B2t; K = 1024; N = 512;
        kb = b & 31; nb = b >> 5;
    }
    int k0 = kb * 32, n0 = nb * 32;
    int tx = t & 31, ty = t >> 5;
    for (int r = ty; r < 32; r += 8) s[r][tx] = W[(size_t)(k0 + r) * N + n0 + tx];
    __syncthreads();
    for (int r = ty; r < 32; r += 8) {
        float v = s[tx][r];
        Bt[(size_t)(n0 + r) * K + k0 + tx] = (short)f2bf(v);
    }
}

// ---------------- CSR scan / scatter ----------------
__global__ void k_scan(const int* __restrict__ counts, int Nn, int ET, int* __restrict__ row_off) {
    __shared__ int lds[256];
    int t = threadIdx.x;
    int chunk = (Nn + 255) / 256;
    int b0 = t * chunk, b1 = min(Nn, b0 + chunk);
    int s = 0;
    for (int i = b0; i < b1; i++) s += counts[i];
    lds[t] = s;
    __syncthreads();
    #pragma unroll
    for (int d = 1; d < 256; d <<= 1) {
        int v = (t >= d) ? lds[t - d] : 0;
        __syncthreads();
        lds[t] += v;
        __syncthreads();
    }
    int run = (t == 0) ? 0 : lds[t - 1];
    for (int i = b0; i < b1; i++) { row_off[i] = run; run += counts[i]; }
    if (t == 0) row_off[Nn] = ET;
}

__global__ void k_scatter(const int* __restrict__ ei, int E, int Nn,
                          const int* __restrict__ row_off, int* cursor, int* __restrict__ col) {
    int e = blockIdx.x * blockDim.x + threadIdx.x;
    int ET = E + Nn;
    if (e >= ET) return;
    int d = (e < E) ? ei[E + e] : (e - E);
    int s = (e < E) ? ei[e] : (e - E);
    int pos = atomicAdd(&cursor[d], 1);
    col[row_off[d] + pos] = s;
}

// ---------------- GEMM: 64x128 tile, BK=32, fused scores. HEADC = head width ----------------
template<int HEADC>
__global__ __launch_bounds__(256) void k_mfma_w(const short* __restrict__ A,
                                                const short* __restrict__ B,
                                                unsigned short* __restrict__ C,
                                                const float* __restrict__ a_src,
                                                const float* __restrict__ a_dst,
                                                float* __restrict__ ssrc,
                                                float* __restrict__ sdst,
                                                int M, int N, int Ktot,
                                                int lda, int ldb) {
    __shared__ short As[64 * 32];
    __shared__ short Bs[128 * 32];
    __shared__ float sred[4][64][2];
    int t = threadIdx.x;
    int lane = t & 63;
    int wid = t >> 6;

    int nbx = N >> 7;
    int nb = gridDim.x;
    int q = nb >> 3, r = nb & 7;
    int xcd = blockIdx.x & 7, pos = blockIdx.x >> 3;
    int L = (xcd < r ? xcd * (q + 1) : r * (q + 1) + (xcd - r) * q) + pos;
    int bn = (L % nbx) * 128;
    int bm = (L / nbx) * 64;

    int wm = (wid & 1) * 32, wn = (wid >> 1) * 64;
    int fr = lane & 15, kq = lane >> 4;

    int srow = t >> 2, sslot = t & 3;
    int sko = ((sslot ^ ((srow >> 1) & 3)) << 3);

    f32x4 acc[2][4] = {};

    for (int k0 = 0; k0 < Ktot; k0 += 32) {
        {
            const short* sa = A + (size_t)(bm + srow) * lda + k0 + sko;
            short* da = As + (size_t)(wid << 6) * 8;
            __builtin_amdgcn_global_load_lds((const __attribute__((address_space(1))) void*)sa,
                                             (__attribute__((address_space(3))) void*)da, 16, 0, 0);
            #pragma unroll
            for (int qq = 0; qq < 2; qq++) {
                int v = qq * 256 + t;
                int rowb = v >> 2, slotb = v & 3;
                int skob = ((slotb ^ ((rowb >> 1) & 3)) << 3);
                const short* sb = B + (size_t)(bn + rowb) * ldb + k0 + skob;
                short* db = Bs + (size_t)(qq * 256 + (wid << 6)) * 8;
                __builtin_amdgcn_global_load_lds((const __attribute__((address_space(1))) void*)sb,
                                                 (__attribute__((address_space(3))) void*)db, 16, 0, 0);
            }
        }
        __syncthreads();
        bf16x8 af[2], bfv[4];
        #pragma unroll
        for (int i = 0; i < 2; i++) {
            int rowa = wm + i * 16 + fr;
            af[i] = *(const bf16x8*)(As + rowa * 32 + ((kq ^ ((rowa >> 1) & 3)) << 3));
        }
        #pragma unroll
        for (int j = 0; j < 4; j++) {
            int rowb = wn + j * 16 + fr;
            bfv[j] = *(const bf16x8*)(Bs + rowb * 32 + ((kq ^ ((rowb >> 1) & 3)) << 3));
        }
        #pragma unroll
        for (int i = 0; i < 2; i++)
            #pragma unroll
            for (int j = 0; j < 4; j++)
                acc[i][j] = __builtin_amdgcn_mfma_f32_16x16x32_bf16(af[i], bfv[j], acc[i][j], 0, 0, 0);
        __syncthreads();
    }
    #pragma unroll
    for (int i = 0; i < 2; i++) {
        int rbase = bm + wm + i * 16 + kq * 4;
        #pragma unroll
        for (int j = 0; j < 4; j++) {
            int colc = bn + wn + j * 16 + fr;
            #pragma unroll
            for (int rg = 0; rg < 4; rg++) {
                int rr = rbase + rg;
                if (rr < M) C[(size_t)rr * N + colc] = f2bf(acc[i][j][rg]);
            }
        }
    }
    // fused scores
    float asv[4], adv[4];
    #pragma unroll
    for (int j = 0; j < 4; j++) {
        int colc = bn + wn + j * 16 + fr;
        asv[j] = a_src[colc];
        adv[j] = a_dst[colc];
    }
    float ps[8], pd[8];
    #pragma unroll
    for (int i = 0; i < 2; i++)
        #pragma unroll
        for (int rg = 0; rg < 4; rg++) {
            int k8 = i * 4 + rg;
            ps[k8] = acc[i][0][rg] * asv[0] + acc[i][1][rg] * asv[1]
                   + acc[i][2][rg] * asv[2] + acc[i][3][rg] * asv[3];
            pd[k8] = acc[i][0][rg] * adv[0] + acc[i][1][rg] * adv[1]
                   + acc[i][2][rg] * adv[2] + acc[i][3][rg] * adv[3];
        }
    #pragma unroll
    for (int k8 = 0; k8 < 8; k8++) {
        #pragma unroll
        for (int off = 1; off < 16; off <<= 1) {
            ps[k8] += __shfl_xor(ps[k8], off);
            pd[k8] += __shfl_xor(pd[k8], off);
        }
    }
    if (HEADC == 128) {
        if (fr == 0) {
            #pragma unroll
            for (int i = 0; i < 2; i++)
                #pragma unroll
                for (int rg = 0; rg < 4; rg++) {
                    int rl = wm + i * 16 + kq * 4 + rg;
                    sred[wid][rl][0] = ps[i * 4 + rg];
                    sred[wid][rl][1] = pd[i * 4 + rg];
                }
        }
        __syncthreads();
        if (wid < 2 && fr == 0) {
            int hh = bn >> 7;
            #pragma unroll
            for (int i = 0; i < 2; i++)
                #pragma unroll
                for (int rg = 0; rg < 4; rg++) {
                    int rl = wm + i * 16 + kq * 4 + rg;
                    int rr = bm + rl;
                    if (rr < M) {
                        ssrc[rr * 8 + hh] = sred[wid][rl][0] + sred[wid + 2][rl][0];
                        sdst[rr * 8 + hh] = sred[wid][rl][1] + sred[wid + 2][rl][1];
                    }
                }
        }
    } else {
        // HEADC==64: this wave's 64 cols = exactly one head; rows disjoint across waves
        int hh = (bn + wn) >> 6;
        if (fr == 0) {
            #pragma unroll
            for (int i = 0; i < 2; i++)
                #pragma unroll
                for (int rg = 0; rg < 4; rg++) {
                    int rr = bm + wm + i * 16 + kq * 4 + rg;
                    if (rr < M) {
                        ssrc[rr * 8 + hh] = ps[i * 4 + rg];
                        sdst[rr * 8 + hh] = pd[i * 4 + rg];
                    }
                }
        }
    }
}

// ---------------- layer-1 aggregation: XCD-sliced, 4 slices of 256 cols ----------------
// block b: xcd=b&7, pos=b>>3; slice=xcd&3 (pinned per XCD -> 5MB L2 working set);
// node = pos*8 + (xcd>>2)*4 + wid. Lane owns 4 cols (uint2 8B loads).
__global__ __launch_bounds__(256) void k_agg1_x(const unsigned short* __restrict__ hsrc,
                                                const float* __restrict__ ssrc,
                                                const float* __restrict__ sdst,
                                                const int* __restrict__ col,
                                                const int* __restrict__ row_off,
                                                const float* __restrict__ bias,
                                                unsigned short* __restrict__ osp,
                                                int Nn) {
    constexpr int D = 1024;
    int lane = threadIdx.x & 63;
    int wid = threadIdx.x >> 6;
    int xcd = blockIdx.x & 7, pos = blockIdx.x >> 3;
    int slice = xcd & 3;
    int n = pos * 8 + ((xcd >> 2) << 2) + wid;
    if (n >= Nn) return;
    int col0 = slice * 256 + lane * 4;
    int myhead = col0 >> 7;                 // C=128
    float sd = sdst[n * 8 + myhead];
    int beg = row_off[n], end = row_off[n + 1];
    const unsigned short* hbase = hsrc + col0;

    float acc[4] = {0.f, 0.f, 0.f, 0.f};
    float den = 0.f;
    #pragma unroll 4
    for (int j = beg; j < end; j++) {
        int cj = col[j];
        float s = ssrc[cj * 8 + myhead] + sd;
        s = (s >= 0.f) ? s : NEG_SLOPE * s;
        float ex = __expf(s);
        den += ex;
        uint2 u = *(const uint2*)(hbase + (size_t)cj * D);
        acc[0] += ex * bflo(u.x); acc[1] += ex * bfhi(u.x);
        acc[2] += ex * bflo(u.y); acc[3] += ex * bfhi(u.y);
    }
    float iv = 1.f / (den + EPS_DEN);
    float vals[4];
    #pragma unroll
    for (int v = 0; v < 4; v++) {
        float val = acc[v] * iv + bias[col0 + v];
        vals[v] = (val > 0.f) ? val : (__expf(val) - 1.f);   // ELU
    }
    uint2 o;
    o.x = (unsigned)f2bf(vals[0]) | ((unsigned)f2bf(vals[1]) << 16);
    o.y = (unsigned)f2bf(vals[2]) | ((unsigned)f2bf(vals[3]) << 16);
    *(uint2*)(osp + (size_t)n * D + col0) = o;
}

// ---------------- layer-2 agg (edge-split 2 waves/node) + ELU + W3 + packed layer-3 state ----------------
__global__ __launch_bounds__(256) void k_agg2_l3(const unsigned short* __restrict__ hsrc,
                                                 const float* __restrict__ ssrc,
                                                 const float* __restrict__ sdst,
                                                 const int* __restrict__ col,
                                                 const int* __restrict__ row_off,
                                                 const float* __restrict__ bias,
                                                 const float* __restrict__ W3,
                                                 const float* __restrict__ as3,
                                                 const float* __restrict__ ad3,
                                                 float4* __restrict__ h3s,
                                                 float* __restrict__ sdst3,
                                                 int Nn) {
    constexpr int D = 512;
    __shared__ float cacc[2][64][9];
    int t = threadIdx.x;
    int lane = t & 63;
    int wid = t >> 6;
    int node_i = wid >> 1, half = wid & 1;
    int n = blockIdx.x * 2 + node_i;
    bool active = (n < Nn);
    int col0 = lane * 8;
    int myhead = lane >> 3;
    float acc[8] = {0.f, 0.f, 0.f, 0.f, 0.f, 0.f, 0.f, 0.f};
    float den = 0.f;
    if (active) {
        float sd = sdst[n * 8 + myhead];
        int beg = row_off[n], end = row_off[n + 1];
        const unsigned short* hbase = hsrc + col0;
        #pragma unroll 4
        for (int j = beg + half; j < end; j += 2) {
            int cj = col[j];
            float s = ssrc[cj * 8 + myhead] + sd;
            s = (s >= 0.f) ? s : NEG_SLOPE * s;
            float ex = __expf(s);
            den += ex;
            uint4 u = *(const uint4*)(hbase + (size_t)cj * D);
            acc[0] += ex * bflo(u.x); acc[1] += ex * bfhi(u.x);
            acc[2] += ex * bflo(u.y); acc[3] += ex * bfhi(u.y);
            acc[4] += ex * bflo(u.z); acc[5] += ex * bfhi(u.z);
            acc[6] += ex * bflo(u.w); acc[7] += ex * bfhi(u.w);
        }
    }
    if (half == 1) {
        #pragma unroll
        for (int v = 0; v < 8; v++) cacc[node_i][lane][v] = acc[v];
        cacc[node_i][lane][8] = den;
    }
    __syncthreads();
    if (half == 0 && active) {
        #pragma unroll
        for (int v = 0; v < 8; v++) acc[v] += cacc[node_i][lane][v];
        den += cacc[node_i][lane][8];
        float iv = 1.f / (den + EPS_DEN);
        float t0 = 0.f, t1 = 0.f, t2 = 0.f;
        #pragma unroll
        for (int v = 0; v < 8; v++) {
            float val = acc[v] * iv + bias[col0 + v];
            val = (val > 0.f) ? val : (__expf(val) - 1.f);
            const float* wp = W3 + (size_t)(col0 + v) * 3;
            t0 += val * wp[0];
            t1 += val * wp[1];
            t2 += val * wp[2];
        }
        #pragma unroll
        for (int off = 32; off >= 1; off >>= 1) {
            t0 += __shfl_xor(t0, off);
            t1 += __shfl_xor(t1, off);
            t2 += __shfl_xor(t2, off);
        }
        if (lane == 0) {
            float s3 = t0 * as3[0] + t1 * as3[1] + t2 * as3[2];
            h3s[n] = make_float4(t0, t1, t2, s3);
            sdst3[n] = t0 * ad3[0] + t1 * ad3[1] + t2 * ad3[2];
        }
    }
}

// ---------------- fused layer-3: 4-lane group per node, packed float4 per edge ----------------
__global__ __launch_bounds__(256) void k_l3_fused(const float4* __restrict__ h3s,
                                                  const float* __restrict__ sdst, const int* __restrict__ col,
                                                  const int* __restrict__ row_off, const float* __restrict__ b3,
                                                  float* __restrict__ out, int Nn) {
    int n = blockIdx.x * 64 + (threadIdx.x >> 2);
    int l4 = threadIdx.x & 3;
    if (n >= Nn) return;
    int beg = row_off[n], end = row_off[n + 1];
    float sd = sdst[n];
    float den = 0.f, a0 = 0.f, a1 = 0.f, a2 = 0.f;
    for (int j = beg + l4; j < end; j += 4) {
        int sI = col[j];
        float4 v = h3s[sI];
        float s = v.w + sd;
        s = fmaxf(s, NEG_SLOPE * s);
        float ex = __expf(s);
        den += ex;
        a0 += ex * v.x;
        a1 += ex * v.y;
        a2 += ex * v.z;
    }
    #pragma unroll
    for (int off = 1; off <= 2; off <<= 1) {
        den += __shfl_xor(den, off);
        a0 += __shfl_xor(a0, off);
        a1 += __shfl_xor(a1, off);
        a2 += __shfl_xor(a2, off);
    }
    if (l4 == 0) {
        float iv = 1.f / (den + EPS_DEN);
        float v0 = a0 * iv + b3[0], v1 = a1 * iv + b3[1], v2 = a2 * iv + b3[2];
        float m = fmaxf(v0, fmaxf(v1, v2));
        float l = logf(__expf(v0 - m) + __expf(v1 - m) + __expf(v2 - m));
        out[n * 3 + 0] = v0 - m - l;
        out[n * 3 + 1] = v1 - m - l;
        out[n * 3 + 2] = v2 - m - l;
    }
}

extern "C" void kernel_launch(void* const* d_in, const int* in_sizes, int n_in,
                              void* d_out, int out_size, void* d_ws, size_t ws_size,
                              hipStream_t stream) {
    (void)n_in; (void)out_size; (void)ws_size;
    const float* x   = (const float*)d_in[0];
    const int*   ei  = (const int*)d_in[1];
    const float* W1  = (const float*)d_in[2];
    const float* as1 = (const float*)d_in[3];
    const float* ad1 = (const float*)d_in[4];
    const float* b1  = (const float*)d_in[5];
    const float* W2  = (const float*)d_in[6];
    const float* as2 = (const float*)d_in[7];
    const float* ad2 = (const float*)d_in[8];
    const float* b2  = (const float*)d_in[9];
    const float* W3  = (const float*)d_in[10];
    const float* as3 = (const float*)d_in[11];
    const float* ad3 = (const float*)d_in[12];
    const float* b3  = (const float*)d_in[13];
    float* out = (float*)d_out;

    const int Nn = in_sizes[0] / 64;   // 10000
    const int E  = in_sizes[1] / 2;    // 160000
    const int ET = E + Nn;
    const int Mp = ((Nn + 127) / 128) * 128;   // 10112

    char* ws = (char*)d_ws;
    size_t off = 0;
    auto alloc = [&](size_t bytes) -> void* {
        void* p = ws + off;
        off = (off + bytes + 255) & ~(size_t)255;
        return p;
    };
    unsigned short* hbuf = (unsigned short*)alloc((size_t)Mp * 1024 * 2);
    unsigned short* A2   = (unsigned short*)alloc((size_t)Mp * 1024 * 2);
    float4* h3s = (float4*)alloc((size_t)Nn * 16);
    short* A1   = (short*)alloc((size_t)Mp * 64 * 2);
    short* B1t  = (short*)alloc((size_t)1024 * 64 * 2);
    short* B2t  = (short*)alloc((size_t)512 * 1024 * 2);
    float* ssrc = (float*)alloc((size_t)Nn * 8 * 4);
    float* sdst = (float*)alloc((size_t)Nn * 8 * 4);
    float* ssrcB= (float*)alloc((size_t)Nn * 8 * 4);
    float* sdstB= (float*)alloc((size_t)Nn * 8 * 4);
    float* sdst3= (float*)alloc((size_t)Nn * 4);
    int* counts = (int*)alloc((size_t)Nn * 2 * 4);
    int* cursor = counts + Nn;
    int* row_off= (int*)alloc((size_t)(Nn + 1) * 4);
    int* colb   = (int*)alloc((size_t)ET * 4);

    hipMemsetAsync(counts, 0, (size_t)Nn * 2 * 4, stream);

    int etb = (ET + 255) / 256;
    int xb = (Mp * 64 + 255) / 256;
    int preb = etb + xb + 64 + 512;
    k_pre<<<preb, 256, 0, stream>>>(ei, E, Nn, counts, x, A1, Mp, W1, B1t, W2, B2t);
    k_scan<<<1, 256, 0, stream>>>(counts, Nn, ET, row_off);
    k_scatter<<<etb, 256, 0, stream>>>(ei, E, Nn, row_off, cursor, colb);

    // ---- layer 1: 64 -> 8x128 concat (plain bf16 GEMM, scores fused) ----
    {
        int nb = (1024 / 128) * (Mp / 64);
        k_mfma_w<128><<<nb, 256, 0, stream>>>(A1, B1t, hbuf, as1, ad1, ssrc, sdst,
                                              Nn, 1024, 64, 64, 64);
        int nblk = (Nn + 7) / 8 * 8;
        k_agg1_x<<<nblk, 256, 0, stream>>>(hbuf, ssrc, sdst, colb, row_off, b1, A2, Nn);
    }
    // ---- layer 2: 1024 -> 8x64 concat (plain bf16 GEMM 64x128 tile, scores fused) ----
    {
        int nb = (512 / 128) * (Mp / 64);
        k_mfma_w<64><<<nb, 256, 0, stream>>>((const short*)A2, B2t, hbuf, as2, ad2, ssrcB, sdstB,
                                             Nn, 512, 1024, 1024, 1024);
        k_agg2_l3<<<(Nn + 1) / 2, 256, 0, stream>>>(hbuf, ssrcB, sdstB, colb, row_off, b2,
                                                    W3, as3, ad3, h3s, sdst3, Nn);
    }
    // ---- layer 3: segment softmax + aggregate + log_softmax ----
    k_l3_fused<<<(Nn + 63) / 64, 256, 0, stream>>>(h3s, sdst3, colb, row_off, b3, out, Nn);
}